// Round 3
// baseline (10374.627 us; speedup 1.0000x reference)
//
#include <hip/hip_runtime.h>
#include <hip/hip_bf16.h>

#define B_ 256
#define S_ 512
#define V_ 32000
#define E_ 1024
#define H_ 1024
#define O_ 512

typedef __hip_bfloat16 bf16;
typedef _Float16 f16;
typedef __attribute__((ext_vector_type(8))) short bf16x8;   // 8 bf16 (4 VGPR)
typedef __attribute__((ext_vector_type(8))) _Float16 f16x8; // 8 f16  (4 VGPR)
typedef __attribute__((ext_vector_type(8))) float f32x8;
typedef __attribute__((ext_vector_type(4))) float f32x4;
typedef __attribute__((ext_vector_type(4))) int i32x4;

__device__ __forceinline__ f32x4 mfma_bf(bf16x8 a, bf16x8 b, f32x4 c) {
  return __builtin_amdgcn_mfma_f32_16x16x32_bf16(a, b, c, 0, 0, 0);
}
__device__ __forceinline__ f32x4 mfma_h(f16x8 a, f16x8 b, f32x4 c) {
  return __builtin_amdgcn_mfma_f32_16x16x32_f16(a, b, c, 0, 0, 0);
}

#if defined(__has_builtin)
#if __has_builtin(__builtin_amdgcn_global_load_lds)
#define HAS_GLL 1
#endif
#endif
#ifndef HAS_GLL
#define HAS_GLL 0
#endif

// ---------------------------------------------------------------------------
// ws layout (bytes). WS_MIN path converts emb on the fly; WS_FULL pre-converts.
#define OFF_HHI   ((size_t)0)             // [2][B][H] bf16  h hi, double-buffered
#define OFF_HLO   ((size_t)1048576)       // [2][B][H] bf16  h lo
#define OFF_CNT   ((size_t)2097152)       // [S+1][8] int
#define OFF_RED   ((size_t)2113792)       // [256 wg][128 thr][8] f32 K-half partials
#define OFF_WHHHI ((size_t)3162368)       // [H][H] bf16
#define OFF_WHHLO ((size_t)5259520)       // [H][H] bf16
#define OFF_WIH   ((size_t)7356672)       // [H][E] f16
#define OFF_WCLF  ((size_t)9453824)       // [O][H] bf16
#define OFF_EMB   ((size_t)10502400)      // [V][E] f16
#define WS_MIN    ((size_t)10502400)
#define WS_FULL   ((size_t)76038400)

// ---------------------------------------------------------------------------
__global__ void init_zero_kernel(i32x4* __restrict__ p, int n4) {
  int i = blockIdx.x * 256 + threadIdx.x;
  if (i < n4) p[i] = (i32x4){0, 0, 0, 0};
}

// f32 -> (bf16 hi, bf16 lo) split: hi+lo carries ~17 mantissa bits.
__global__ void k_split_bf16(const float* __restrict__ s, bf16* __restrict__ hi,
                             bf16* __restrict__ lo, int n) {
  int i = blockIdx.x * 256 + threadIdx.x;
  if (i < n) {
    float v = s[i];
    bf16 h = __float2bfloat16(v);
    hi[i] = h;
    lo[i] = __float2bfloat16(v - __bfloat162float(h));
  }
}

__global__ void k_cvt_f16(const float* __restrict__ s, f16* __restrict__ d, int n) {
  int i = blockIdx.x * 256 + threadIdx.x;
  if (i < n) d[i] = (f16)s[i];
}

__global__ void k_cvt_bf16(const float* __restrict__ s, bf16* __restrict__ d, int n) {
  int i = blockIdx.x * 256 + threadIdx.x;
  if (i < n) d[i] = __float2bfloat16(s[i]);
}

// ---------------------------------------------------------------------------
// Persistent fused RNN scan. 256 WGs = 8 row-groups (gi: 32 batch rows) x 32
// col-groups (gj: 32 h cols). 4 waves = 2 row-halves (wm) x 2 K-halves (kh).
// Per step, each wave computes a 16x32 tile over its K-half:
//   acc  = xe_t @ Wih^T        (f16 single-pass; no cross-WG dependency)
//   wait for all 32 producers of h_t rows [gi]  (per-(step,group) counter)
//   acc += h_t @ Whh^T          (bf16 3-pass split: Ah*Wh + Al*Wh + Ah*Wl)
// K-halves reduced via a per-WG global scratch + __syncthreads (workgroup
// barrier guarantees global-store visibility within the block).
// Weight residency: Whh-hi slice in 64KB swizzled LDS (whole kernel);
// Whh-lo + Wih f16 fragments in registers (~256 VGPRs) -> 1 wave/SIMD,
// 1 WG/CU, all 256 WGs co-resident on 256 CUs (no deadlock).
// gi = blockIdx.x & 7: round-robin dispatch co-locates a row group per XCD
// (L2 locality heuristic only; correctness uses agent-scope atomics/fences).
__global__ __launch_bounds__(256, 1) void rnn_scan(
    const int* __restrict__ x,           // [B][S]
    const float* __restrict__ emb_f32,   // [V][E] f32
    const f16* __restrict__ emb_h,       // [V][E] f16 (optional)
    const int use_f16_emb,
    const f16* __restrict__ wih_h,       // [H][E] f16
    const float* __restrict__ bih, const float* __restrict__ bhh,
    const bf16* __restrict__ whh_hi_g,   // [H][H]
    const bf16* __restrict__ whh_lo_g,   // [H][H]
    bf16* __restrict__ h_hi, bf16* __restrict__ h_lo,  // [2][B][H]
    int* __restrict__ cnt, float* __restrict__ red) {
  __shared__ short Wl[32 * 1024];  // Whh-hi slice, 16B-chunk XOR swizzle

  const int tid = threadIdx.x, lane = tid & 63;
  const int w = tid >> 6, wm = w & 1, kh = w >> 1;
  const int gi = blockIdx.x & 7, gj = blockIdx.x >> 3;
  const int m0 = gi * 32, n0 = gj * 32;
  const int am = lane & 15, akc = lane >> 4;

  // Stage Whh-hi rows (= h-cols) n0..n0+31, chunk c -> c ^ (row&7)
  for (int q = tid; q < 32 * 128; q += 256) {
    int rr = q >> 7, c = q & 127;
    *(bf16x8*)&Wl[rr * 1024 + (c ^ (rr & 7)) * 8] =
        *(const bf16x8*)&whh_hi_g[(size_t)(n0 + rr) * H_ + c * 8];
  }

  // Register-resident B-fragments for this wave's K-half (kh*512..+512):
  // Whh-lo (bf16) and Wih (f16), for both 16-col tiles ct=0,1.
  bf16x8 wlo[2][16];
  f16x8 wih[2][16];
  float bsum[2];
  int nl[2];
#pragma unroll
  for (int ct = 0; ct < 2; ++ct) {
    const int n = n0 + ct * 16 + am;
    nl[ct] = ct * 16 + am;
    bsum[ct] = bih[n] + bhh[n];
#pragma unroll
    for (int kc = 0; kc < 16; ++kc) {
      const int k = kh * 512 + kc * 32 + akc * 8;
      wlo[ct][kc] = *(const bf16x8*)&whh_lo_g[(size_t)n * H_ + k];
      wih[ct][kc] = *(const f16x8*)&wih_h[(size_t)n * E_ + k];
    }
  }
  __syncthreads();

  const int arow = m0 + wm * 16 + am;  // this lane's A-frag batch row
  const int koff = kh * 512 + akc * 8;
  // D layout (m89/m91): col = lane&15, row = (lane>>4)*4 + reg
  const int mG = m0 + wm * 16 + (lane >> 4) * 4;
  const int nG0 = n0 + (lane & 15), nG1 = n0 + 16 + (lane & 15);
  float* redp = red + ((size_t)blockIdx.x * 128 + (tid & 127)) * 8;

  for (int t = 0; t < S_; ++t) {
    f32x4 acc0 = {0.f, 0.f, 0.f, 0.f}, acc1 = {0.f, 0.f, 0.f, 0.f};

    // ---- input projection (f16), independent of other WGs: hides the wait
    const int idx = x[arow * S_ + t];
    if (use_f16_emb) {
      const f16* er = emb_h + (size_t)idx * E_ + koff;
#pragma unroll
      for (int kc = 0; kc < 16; ++kc) {
        f16x8 a = *(const f16x8*)(er + kc * 32);
        acc0 = mfma_h(a, wih[0][kc], acc0);
        acc1 = mfma_h(a, wih[1][kc], acc1);
      }
    } else {
      const float* er = emb_f32 + (size_t)idx * E_ + koff;
#pragma unroll
      for (int kc = 0; kc < 16; ++kc) {
        f32x8 v = *(const f32x8*)(er + kc * 32);  // 32B aligned
        f16x8 a = __builtin_convertvector(v, f16x8);
        acc0 = mfma_h(a, wih[0][kc], acc0);
        acc1 = mfma_h(a, wih[1][kc], acc1);
      }
    }

    // ---- wait for step-t h rows of this group (32 producers)
    if (t > 0) {
      while (__hip_atomic_load(&cnt[t * 8 + gi], __ATOMIC_RELAXED,
                               __HIP_MEMORY_SCOPE_AGENT) < 32)
        __builtin_amdgcn_s_sleep(2);
      __builtin_amdgcn_fence(__ATOMIC_ACQUIRE, "agent");
    }

    // ---- recurrent: h_t @ Whh^T, bf16 3-pass split
    const bf16* ah = h_hi + (size_t)(t & 1) * (B_ * H_) + (size_t)arow * H_ + koff;
    const bf16* al = h_lo + (size_t)(t & 1) * (B_ * H_) + (size_t)arow * H_ + koff;
#pragma unroll
    for (int kc = 0; kc < 16; ++kc) {
      bf16x8 ahi = *(const bf16x8*)(ah + kc * 32);
      bf16x8 alo = *(const bf16x8*)(al + kc * 32);
      const int cidx = kh * 64 + kc * 4 + akc;
      bf16x8 b0 = *(const bf16x8*)&Wl[nl[0] * 1024 + (cidx ^ (nl[0] & 7)) * 8];
      bf16x8 b1 = *(const bf16x8*)&Wl[nl[1] * 1024 + (cidx ^ (nl[1] & 7)) * 8];
      acc0 = mfma_bf(ahi, b0, acc0);
      acc0 = mfma_bf(alo, b0, acc0);
      acc0 = mfma_bf(ahi, wlo[0][kc], acc0);
      acc1 = mfma_bf(ahi, b1, acc1);
      acc1 = mfma_bf(alo, b1, acc1);
      acc1 = mfma_bf(ahi, wlo[1][kc], acc1);
    }

    // ---- K-half reduction via global scratch (barrier gives visibility)
    if (kh == 1) {
      *(f32x4*)redp = acc0;
      *(f32x4*)(redp + 4) = acc1;
    }
    __syncthreads();
    if (kh == 0) {
      acc0 += *(const f32x4*)redp;  // partner (tid+128) wrote slot tid
      acc1 += *(const f32x4*)(redp + 4);
      bf16* hd_hi = h_hi + (size_t)((t + 1) & 1) * (B_ * H_);
      bf16* hd_lo = h_lo + (size_t)((t + 1) & 1) * (B_ * H_);
#pragma unroll
      for (int r = 0; r < 4; ++r) {
        float th0 = tanhf(acc0[r] + bsum[0]);
        bf16 c0 = __float2bfloat16(th0);
        hd_hi[(size_t)(mG + r) * H_ + nG0] = c0;
        hd_lo[(size_t)(mG + r) * H_ + nG0] =
            __float2bfloat16(th0 - __bfloat162float(c0));
        float th1 = tanhf(acc1[r] + bsum[1]);
        bf16 c1 = __float2bfloat16(th1);
        hd_hi[(size_t)(mG + r) * H_ + nG1] = c1;
        hd_lo[(size_t)(mG + r) * H_ + nG1] =
            __float2bfloat16(th1 - __bfloat162float(c1));
      }
    }
    __syncthreads();  // h stores drained (vmcnt 0) before signal
    if (tid == 0)
      __hip_atomic_fetch_add(&cnt[(t + 1) * 8 + gi], 1, __ATOMIC_RELEASE,
                             __HIP_MEMORY_SCOPE_AGENT);
  }
}

// ---------------------------------------------------------------------------
// 128x128-tile bf16 GEMM (m97 structure): out[r][n] = sum_k A[r][k]*Bw[n][k]
// + bias[n]. f32 bias, f32 out. One-shot bf16 error ~1e-3 << threshold.
__global__ __launch_bounds__(256, 2) void gemm_bias_kernel(
    const bf16* __restrict__ A, const bf16* __restrict__ Bw,
    const float* __restrict__ bias, float* __restrict__ Cc, int Ndim, int Kdim) {
  __shared__ bf16 At[128 * 64];
  __shared__ bf16 Bt[128 * 64];

  const int tid = threadIdx.x;
  const int wave = tid >> 6, lane = tid & 63;
  const int row0 = blockIdx.y * 128, col0 = blockIdx.x * 128;
  const int wm = wave & 1, wn = wave >> 1;

  f32x4 acc[4][4];
#pragma unroll
  for (int mi = 0; mi < 4; ++mi)
#pragma unroll
    for (int ni = 0; ni < 4; ++ni) acc[mi][ni] = (f32x4){0.f, 0.f, 0.f, 0.f};

  for (int kb = 0; kb < Kdim; kb += 64) {
#pragma unroll
    for (int it = 0; it < 4; ++it) {
      int q = it * 256 + tid;
      int rr = q >> 3, qc = (q & 7) * 8;
      const bf16* ga = A + (size_t)(row0 + rr) * Kdim + kb + qc;
      const bf16* gb = Bw + (size_t)(col0 + rr) * Kdim + kb + qc;
#if HAS_GLL
      __builtin_amdgcn_global_load_lds(
          (const __attribute__((address_space(1))) void*)ga,
          (__attribute__((address_space(3))) void*)((char*)At + (it * 4 + wave) * 1024),
          16, 0, 0);
      __builtin_amdgcn_global_load_lds(
          (const __attribute__((address_space(1))) void*)gb,
          (__attribute__((address_space(3))) void*)((char*)Bt + (it * 4 + wave) * 1024),
          16, 0, 0);
#else
      *(i32x4*)((char*)At + q * 16) = *(const i32x4*)ga;
      *(i32x4*)((char*)Bt + q * 16) = *(const i32x4*)gb;
#endif
    }
    __syncthreads();

#pragma unroll
    for (int ks = 0; ks < 2; ++ks) {
      const int ko = ks * 32 + (lane >> 4) * 8;
      bf16x8 af[4], bfr[4];
#pragma unroll
      for (int mi = 0; mi < 4; ++mi)
        af[mi] = *(const bf16x8*)&At[(wm * 64 + mi * 16 + (lane & 15)) * 64 + ko];
#pragma unroll
      for (int ni = 0; ni < 4; ++ni)
        bfr[ni] = *(const bf16x8*)&Bt[(wn * 64 + ni * 16 + (lane & 15)) * 64 + ko];
#pragma unroll
      for (int mi = 0; mi < 4; ++mi)
#pragma unroll
        for (int ni = 0; ni < 4; ++ni)
          acc[mi][ni] = mfma_bf(af[mi], bfr[ni], acc[mi][ni]);
    }
    __syncthreads();
  }

  const int crow = (lane >> 4) * 4, ccol = lane & 15;
#pragma unroll
  for (int ni = 0; ni < 4; ++ni) {
    const int gc = col0 + wn * 64 + ni * 16 + ccol;
    const float bv = bias[gc];
#pragma unroll
    for (int mi = 0; mi < 4; ++mi) {
      const int gr0 = row0 + wm * 64 + mi * 16 + crow;
#pragma unroll
      for (int r = 0; r < 4; ++r)
        Cc[(size_t)(gr0 + r) * Ndim + gc] = acc[mi][ni][r] + bv;
    }
  }
}

// ---------------------------------------------------------------------------
extern "C" void kernel_launch(void* const* d_in, const int* in_sizes, int n_in,
                              void* d_out, int out_size, void* d_ws, size_t ws_size,
                              hipStream_t stream) {
  const int*   x    = (const int*)d_in[0];
  const float* emb  = (const float*)d_in[1];
  const float* Wih  = (const float*)d_in[2];
  const float* bih  = (const float*)d_in[3];
  const float* Whh  = (const float*)d_in[4];
  const float* bhh  = (const float*)d_in[5];
  const float* Wclf = (const float*)d_in[6];
  const float* bclf = (const float*)d_in[7];
  float* out = (float*)d_out;

  char* ws = (char*)d_ws;
  bf16* h_hi   = (bf16*)(ws + OFF_HHI);
  bf16* h_lo   = (bf16*)(ws + OFF_HLO);
  int*  cnt    = (int*)(ws + OFF_CNT);
  float* red   = (float*)(ws + OFF_RED);
  bf16* whh_hi = (bf16*)(ws + OFF_WHHHI);
  bf16* whh_lo = (bf16*)(ws + OFF_WHHLO);
  f16*  wih_h  = (f16*)(ws + OFF_WIH);
  bf16* wclf_b = (bf16*)(ws + OFF_WCLF);
  f16*  emb_h  = (f16*)(ws + OFF_EMB);
  const int use_f16_emb = (ws_size >= WS_FULL) ? 1 : 0;  // constant per session

  // zero h double-buffers + counters: 2,113,568 B / 16 = 132,098 int4
  init_zero_kernel<<<dim3(517), dim3(256), 0, stream>>>((i32x4*)ws, 132098);

  // weight conversions (f32 inputs -> MFMA-ready formats in ws)
  k_split_bf16<<<dim3(4096), dim3(256), 0, stream>>>(Whh, whh_hi, whh_lo, H_ * H_);
  k_cvt_f16<<<dim3(4096), dim3(256), 0, stream>>>(Wih, wih_h, H_ * E_);
  k_cvt_bf16<<<dim3(2048), dim3(256), 0, stream>>>(Wclf, wclf_b, O_ * H_);
  if (use_f16_emb)
    k_cvt_f16<<<dim3((V_ * E_ + 255) / 256), dim3(256), 0, stream>>>(emb, emb_h,
                                                                     V_ * E_);

  // 512-step fused scan; final h lands in buffer (512)&1 == 0
  rnn_scan<<<dim3(256), dim3(256), 0, stream>>>(
      x, emb, emb_h, use_f16_emb, wih_h, bih, bhh, whh_hi, whh_lo, h_hi, h_lo,
      cnt, red);

  // out[b][o] = sum_k h[b][k] * Wclf[o][k] + bclf[o]
  gemm_bias_kernel<<<dim3(O_ / 128, B_ / 128), dim3(256), 0, stream>>>(
      h_hi, wclf_b, bclf, out, O_, H_);
}

// Round 4
// 4541.706 us; speedup vs baseline: 2.2843x; 2.2843x over previous
//
#include <hip/hip_runtime.h>
#include <hip/hip_bf16.h>

#define B_ 256
#define S_ 512
#define V_ 32000
#define E_ 1024
#define H_ 1024
#define O_ 512

typedef __hip_bfloat16 bf16;
typedef _Float16 f16;
typedef unsigned long long u64;
typedef __attribute__((ext_vector_type(8))) short bf16x8;   // 8 bf16 (4 VGPR)
typedef __attribute__((ext_vector_type(8))) _Float16 f16x8; // 8 f16  (4 VGPR)
typedef __attribute__((ext_vector_type(8))) float f32x8;
typedef __attribute__((ext_vector_type(4))) float f32x4;
typedef __attribute__((ext_vector_type(4))) int i32x4;

__device__ __forceinline__ f32x4 mfma_bf(bf16x8 a, bf16x8 b, f32x4 c) {
  return __builtin_amdgcn_mfma_f32_16x16x32_bf16(a, b, c, 0, 0, 0);
}
__device__ __forceinline__ f32x4 mfma_h(f16x8 a, f16x8 b, f32x4 c) {
  return __builtin_amdgcn_mfma_f32_16x16x32_f16(a, b, c, 0, 0, 0);
}

#if defined(__has_builtin)
#if __has_builtin(__builtin_amdgcn_global_load_lds)
#define HAS_GLL 1
#endif
#endif
#ifndef HAS_GLL
#define HAS_GLL 0
#endif

// ---------------------------------------------------------------------------
// ws layout (bytes)
#define OFF_H     ((size_t)0)             // [2][B][H] bf16 h double-buffer (1 MB)
#define OFF_CNT   ((size_t)1048576)       // [S+1][8] int (16416 B, padded)
#define OFF_WHHHI ((size_t)1081344)       // [H][H] bf16 (2 MB)
#define OFF_WHHLO ((size_t)3178496)       // [H][H] bf16 (2 MB)
#define OFF_WIH   ((size_t)5275648)       // [H][E] f16 (2 MB)
#define OFF_WCLF  ((size_t)7372800)       // [O][H] bf16 (1 MB)
#define OFF_EMB   ((size_t)8421376)       // [V][E] f16 (62.5 MB)
#define WS_MIN    ((size_t)8421376)
#define WS_FULL   ((size_t)73957376)

// ---------------------------------------------------------------------------
__global__ void init_zero_kernel(i32x4* __restrict__ p, int n4) {
  int i = blockIdx.x * 256 + threadIdx.x;
  if (i < n4) p[i] = (i32x4){0, 0, 0, 0};
}

// f32 -> (bf16 hi, bf16 lo) split: hi+lo carries ~17 mantissa bits.
__global__ void k_split_bf16(const float* __restrict__ s, bf16* __restrict__ hi,
                             bf16* __restrict__ lo, int n) {
  int i = blockIdx.x * 256 + threadIdx.x;
  if (i < n) {
    float v = s[i];
    bf16 h = __float2bfloat16(v);
    hi[i] = h;
    lo[i] = __float2bfloat16(v - __bfloat162float(h));
  }
}

__global__ void k_cvt_f16(const float* __restrict__ s, f16* __restrict__ d, int n) {
  int i = blockIdx.x * 256 + threadIdx.x;
  if (i < n) d[i] = (f16)s[i];
}

__global__ void k_cvt_bf16(const float* __restrict__ s, bf16* __restrict__ d, int n) {
  int i = blockIdx.x * 256 + threadIdx.x;
  if (i < n) d[i] = __float2bfloat16(s[i]);
}

// ---------------------------------------------------------------------------
// Persistent fused RNN scan, round 4: NO agent fences (they cost ~20 us/step
// in L2 wb/inv). All h traffic is device-scope (sc0/sc1, L2-bypass
// write-through) via __hip_atomic_* RELAXED/AGENT; release ordering =
// __syncthreads vmcnt-drain + relaxed fetch_add at L3; acquire = relaxed poll
// + workgroup-scope fence (waitcnt only, compiler barrier, no cache ops).
// L2 stays warm for emb/x/weights the whole kernel.
// 256 WGs = 8 row-groups (gi) x 32 col-groups (gj); 4 waves = 2 row-halves
// (wm) x 2 K-halves (kh). h carried as single bf16 (error budget 4.6x at r3);
// recurrent is 2-pass split: h*Whh_hi (LDS, swizzled) + h*Whh_lo (registers).
// K-half reduction through LDS (was: global scratch = 512 MB of HBM writes).
__global__ __launch_bounds__(256, 1) void rnn_scan(
    const int* __restrict__ x,           // [B][S]
    const float* __restrict__ emb_f32,   // [V][E] f32
    const f16* __restrict__ emb_h,       // [V][E] f16 (optional)
    const int use_f16_emb,
    const f16* __restrict__ wih_h,       // [H][E] f16
    const float* __restrict__ bih, const float* __restrict__ bhh,
    const bf16* __restrict__ whh_hi_g,   // [H][H]
    const bf16* __restrict__ whh_lo_g,   // [H][H]
    bf16* __restrict__ hbuf,             // [2][B][H]
    int* __restrict__ cnt) {             // [S+1][8]
  __shared__ short Wl[32 * 1024];  // Whh-hi slice, 16B-chunk XOR swizzle (64 KB)
  __shared__ f32x4 redA[128];      // kh1 -> kh0 partials (tile0)
  __shared__ f32x4 redB[128];      // kh0 -> kh1 partials (tile1)

  const int tid = threadIdx.x, lane = tid & 63;
  const int w = tid >> 6, wm = w & 1, kh = w >> 1;
  const int gi = blockIdx.x & 7, gj = blockIdx.x >> 3;
  const int m0 = gi * 32, n0 = gj * 32;
  const int am = lane & 15, akc = lane >> 4;

  // Stage Whh-hi rows (= h-cols) n0..n0+31, chunk c -> c ^ (row & 7)
  for (int q = tid; q < 32 * 128; q += 256) {
    int rr = q >> 7, c = q & 127;
    *(bf16x8*)&Wl[rr * 1024 + (c ^ (rr & 7)) * 8] =
        *(const bf16x8*)&whh_hi_g[(size_t)(n0 + rr) * H_ + c * 8];
  }

  // Register-resident fragments for this wave's K-half: Whh-lo + Wih f16.
  bf16x8 wlo[2][16];
  f16x8 wih[2][16];
  float bsum[2];
  int nl[2];
#pragma unroll
  for (int ct = 0; ct < 2; ++ct) {
    const int n = n0 + ct * 16 + am;
    nl[ct] = ct * 16 + am;
    bsum[ct] = bih[n] + bhh[n];
#pragma unroll
    for (int kc = 0; kc < 16; ++kc) {
      const int k = kh * 512 + kc * 32 + akc * 8;
      wlo[ct][kc] = *(const bf16x8*)&whh_lo_g[(size_t)n * H_ + k];
      wih[ct][kc] = *(const f16x8*)&wih_h[(size_t)n * E_ + k];
    }
  }
  __syncthreads();

  const int arow = m0 + wm * 16 + am;  // this lane's A-frag batch row
  const int koff = kh * 512 + akc * 8;
  // D layout (m89/m91): col = lane&15, row = (lane>>4)*4 + reg
  const int mG = m0 + wm * 16 + (lane >> 4) * 4;
  const int myct = kh;                       // kh0 finalizes tile0, kh1 tile1
  const int nGm = n0 + myct * 16 + am;       // my store column

  union cvt8 { u64 q[2]; bf16x8 v; };

  for (int t = 0; t < S_; ++t) {
    f32x4 a0a = {0.f,0.f,0.f,0.f}, a0b = {0.f,0.f,0.f,0.f};
    f32x4 a1a = {0.f,0.f,0.f,0.f}, a1b = {0.f,0.f,0.f,0.f};

    // ---- input projection (f16, cached loads): hides the wait below
    const int idx = x[arow * S_ + t];
    if (use_f16_emb) {
      const f16* er = emb_h + (size_t)idx * E_ + koff;
#pragma unroll
      for (int kc = 0; kc < 16; ++kc) {
        f16x8 a = *(const f16x8*)(er + kc * 32);
        a0a = mfma_h(a, wih[0][kc], a0a);
        a1a = mfma_h(a, wih[1][kc], a1a);
      }
    } else {
      const float* er = emb_f32 + (size_t)idx * E_ + koff;
#pragma unroll
      for (int kc = 0; kc < 16; ++kc) {
        f32x8 v = *(const f32x8*)(er + kc * 32);
        f16x8 a = __builtin_convertvector(v, f16x8);
        a0a = mfma_h(a, wih[0][kc], a0a);
        a1a = mfma_h(a, wih[1][kc], a1a);
      }
    }

    // ---- wait for step-t h rows of this group (32 producers)
    if (t > 0) {
      while (__hip_atomic_load(&cnt[t * 8 + gi], __ATOMIC_RELAXED,
                               __HIP_MEMORY_SCOPE_AGENT) < 32)
        __builtin_amdgcn_s_sleep(1);
      __builtin_amdgcn_fence(__ATOMIC_ACQUIRE, "workgroup");  // waitcnt only
    }

    // ---- h row fragment: 32 independent 8B device-scope loads (L3-fresh),
    // issued up-front so they pipeline; compiler inserts fine-grained vmcnt.
    const u64* hsrc = (const u64*)(hbuf + (size_t)(t & 1) * (B_ * H_) +
                                   (size_t)arow * H_ + koff);
    u64 hb[32];
#pragma unroll
    for (int kc = 0; kc < 16; ++kc) {
      hb[2 * kc]     = __hip_atomic_load(hsrc + kc * 8, __ATOMIC_RELAXED,
                                         __HIP_MEMORY_SCOPE_AGENT);
      hb[2 * kc + 1] = __hip_atomic_load(hsrc + kc * 8 + 1, __ATOMIC_RELAXED,
                                         __HIP_MEMORY_SCOPE_AGENT);
    }

    // ---- recurrent: h @ Whh^T, 2-pass (hi from LDS, lo from registers)
#pragma unroll
    for (int kc = 0; kc < 16; ++kc) {
      cvt8 c;
      c.q[0] = hb[2 * kc];
      c.q[1] = hb[2 * kc + 1];
      bf16x8 a = c.v;
      const int cidx = kh * 64 + kc * 4 + akc;
      bf16x8 b0 = *(const bf16x8*)&Wl[nl[0] * 1024 + (cidx ^ (nl[0] & 7)) * 8];
      bf16x8 b1 = *(const bf16x8*)&Wl[nl[1] * 1024 + (cidx ^ (nl[1] & 7)) * 8];
      a0a = mfma_bf(a, b0, a0a);
      a0b = mfma_bf(a, wlo[0][kc], a0b);
      a1a = mfma_bf(a, b1, a1a);
      a1b = mfma_bf(a, wlo[1][kc], a1b);
    }

    // ---- K-half exchange through LDS; each half finalizes one 16-col tile
    f32x4 acc0 = a0a + a0b, acc1 = a1a + a1b;
    if (kh == 1) redA[tid & 127] = acc0; else redB[tid] = acc1;
    __syncthreads();
    f32x4 fin = (kh == 0) ? (acc0 + redA[tid]) : (acc1 + redB[tid & 127]);

    // ---- tanh + device-scope write-through h store
    bf16* hdst = hbuf + (size_t)((t + 1) & 1) * (B_ * H_);
    const float bs = bsum[myct];
#pragma unroll
    for (int r = 0; r < 4; ++r) {
      bf16 hv = __float2bfloat16(tanhf(fin[r] + bs));
      __hip_atomic_store((unsigned short*)&hdst[(size_t)(mG + r) * H_ + nGm],
                         (unsigned short)__bfloat16_as_ushort(hv),
                         __ATOMIC_RELAXED, __HIP_MEMORY_SCOPE_AGENT);
    }

    __syncthreads();  // vmcnt(0) drain: all WG h stores acked at coherence pt
    if (tid == 0)
      __hip_atomic_fetch_add(&cnt[(t + 1) * 8 + gi], 1, __ATOMIC_RELAXED,
                             __HIP_MEMORY_SCOPE_AGENT);
  }
}

// ---------------------------------------------------------------------------
// 128x128-tile bf16 GEMM (m97 structure): out[r][n] = sum_k A[r][k]*Bw[n][k]
// + bias[n]. f32 bias, f32 out.
__global__ __launch_bounds__(256, 2) void gemm_bias_kernel(
    const bf16* __restrict__ A, const bf16* __restrict__ Bw,
    const float* __restrict__ bias, float* __restrict__ Cc, int Ndim, int Kdim) {
  __shared__ bf16 At[128 * 64];
  __shared__ bf16 Bt[128 * 64];

  const int tid = threadIdx.x;
  const int wave = tid >> 6, lane = tid & 63;
  const int row0 = blockIdx.y * 128, col0 = blockIdx.x * 128;
  const int wm = wave & 1, wn = wave >> 1;

  f32x4 acc[4][4];
#pragma unroll
  for (int mi = 0; mi < 4; ++mi)
#pragma unroll
    for (int ni = 0; ni < 4; ++ni) acc[mi][ni] = (f32x4){0.f, 0.f, 0.f, 0.f};

  for (int kb = 0; kb < Kdim; kb += 64) {
#pragma unroll
    for (int it = 0; it < 4; ++it) {
      int q = it * 256 + tid;
      int rr = q >> 3, qc = (q & 7) * 8;
      const bf16* ga = A + (size_t)(row0 + rr) * Kdim + kb + qc;
      const bf16* gb = Bw + (size_t)(col0 + rr) * Kdim + kb + qc;
#if HAS_GLL
      __builtin_amdgcn_global_load_lds(
          (const __attribute__((address_space(1))) void*)ga,
          (__attribute__((address_space(3))) void*)((char*)At + (it * 4 + wave) * 1024),
          16, 0, 0);
      __builtin_amdgcn_global_load_lds(
          (const __attribute__((address_space(1))) void*)gb,
          (__attribute__((address_space(3))) void*)((char*)Bt + (it * 4 + wave) * 1024),
          16, 0, 0);
#else
      *(i32x4*)((char*)At + q * 16) = *(const i32x4*)ga;
      *(i32x4*)((char*)Bt + q * 16) = *(const i32x4*)gb;
#endif
    }
    __syncthreads();

#pragma unroll
    for (int ks = 0; ks < 2; ++ks) {
      const int ko = ks * 32 + (lane >> 4) * 8;
      bf16x8 af[4], bfr[4];
#pragma unroll
      for (int mi = 0; mi < 4; ++mi)
        af[mi] = *(const bf16x8*)&At[(wm * 64 + mi * 16 + (lane & 15)) * 64 + ko];
#pragma unroll
      for (int ni = 0; ni < 4; ++ni)
        bfr[ni] = *(const bf16x8*)&Bt[(wn * 64 + ni * 16 + (lane & 15)) * 64 + ko];
#pragma unroll
      for (int mi = 0; mi < 4; ++mi)
#pragma unroll
        for (int ni = 0; ni < 4; ++ni)
          acc[mi][ni] = mfma_bf(af[mi], bfr[ni], acc[mi][ni]);
    }
    __syncthreads();
  }

  const int crow = (lane >> 4) * 4, ccol = lane & 15;
#pragma unroll
  for (int ni = 0; ni < 4; ++ni) {
    const int gc = col0 + wn * 64 + ni * 16 + ccol;
    const float bv = bias[gc];
#pragma unroll
    for (int mi = 0; mi < 4; ++mi) {
      const int gr0 = row0 + wm * 64 + mi * 16 + crow;
#pragma unroll
      for (int r = 0; r < 4; ++r)
        Cc[(size_t)(gr0 + r) * Ndim + gc] = acc[mi][ni][r] + bv;
    }
  }
}

// ---------------------------------------------------------------------------
extern "C" void kernel_launch(void* const* d_in, const int* in_sizes, int n_in,
                              void* d_out, int out_size, void* d_ws, size_t ws_size,
                              hipStream_t stream) {
  const int*   x    = (const int*)d_in[0];
  const float* emb  = (const float*)d_in[1];
  const float* Wih  = (const float*)d_in[2];
  const float* bih  = (const float*)d_in[3];
  const float* Whh  = (const float*)d_in[4];
  const float* bhh  = (const float*)d_in[5];
  const float* Wclf = (const float*)d_in[6];
  const float* bclf = (const float*)d_in[7];
  float* out = (float*)d_out;

  char* ws = (char*)d_ws;
  bf16* hbuf   = (bf16*)(ws + OFF_H);
  int*  cnt    = (int*)(ws + OFF_CNT);
  bf16* whh_hi = (bf16*)(ws + OFF_WHHHI);
  bf16* whh_lo = (bf16*)(ws + OFF_WHHLO);
  f16*  wih_h  = (f16*)(ws + OFF_WIH);
  bf16* wclf_b = (bf16*)(ws + OFF_WCLF);
  f16*  emb_h  = (f16*)(ws + OFF_EMB);
  const int use_f16_emb = (ws_size >= WS_FULL) ? 1 : 0;  // constant per session

  // zero hbuf + cnt: (1048576 + 16416)/16 = 66562 int4s
  init_zero_kernel<<<dim3(261), dim3(256), 0, stream>>>((i32x4*)ws, 66562);

  // weight conversions (f32 inputs -> MFMA-ready formats in ws)
  k_split_bf16<<<dim3(4096), dim3(256), 0, stream>>>(Whh, whh_hi, whh_lo, H_ * H_);
  k_cvt_f16<<<dim3(4096), dim3(256), 0, stream>>>(Wih, wih_h, H_ * E_);
  k_cvt_bf16<<<dim3(2048), dim3(256), 0, stream>>>(Wclf, wclf_b, O_ * H_);
  if (use_f16_emb)
    k_cvt_f16<<<dim3((V_ * E_ + 255) / 256), dim3(256), 0, stream>>>(emb, emb_h,
                                                                     V_ * E_);

  // 512-step fused scan; final h lands in buffer (512)&1 == 0
  rnn_scan<<<dim3(256), dim3(256), 0, stream>>>(
      x, emb, emb_h, use_f16_emb, wih_h, bih, bhh, whh_hi, whh_lo, hbuf, cnt);

  // out[b][o] = sum_k h[b][k] * Wclf[o][k] + bclf[o]
  gemm_bias_kernel<<<dim3(O_ / 128, B_ / 128), dim3(256), 0, stream>>>(
      hbuf, wclf_b, bclf, out, O_, H_);
}

// Round 6
// 4407.675 us; speedup vs baseline: 2.3538x; 1.0304x over previous
//
#include <hip/hip_runtime.h>
#include <hip/hip_bf16.h>

#define B_ 256
#define S_ 512
#define V_ 32000
#define E_ 1024
#define H_ 1024
#define O_ 512

typedef __hip_bfloat16 bf16;
typedef _Float16 f16;
typedef __attribute__((ext_vector_type(8))) short bf16x8;   // 8 bf16 (4 VGPR)
typedef __attribute__((ext_vector_type(8))) _Float16 f16x8; // 8 f16  (4 VGPR)
typedef __attribute__((ext_vector_type(8))) float f32x8;
typedef __attribute__((ext_vector_type(4))) float f32x4;
typedef __attribute__((ext_vector_type(4))) int i32x4;

union icast { i32x4 i; bf16x8 h; };

__device__ __forceinline__ f32x4 mfma_bf(bf16x8 a, bf16x8 b, f32x4 c) {
  return __builtin_amdgcn_mfma_f32_16x16x32_bf16(a, b, c, 0, 0, 0);
}
__device__ __forceinline__ f32x4 mfma_h(f16x8 a, f16x8 b, f32x4 c) {
  return __builtin_amdgcn_mfma_f32_16x16x32_f16(a, b, c, 0, 0, 0);
}

#if defined(__has_builtin)
#if __has_builtin(__builtin_amdgcn_global_load_lds)
#define HAS_GLL 1
#endif
#endif
#ifndef HAS_GLL
#define HAS_GLL 0
#endif

// ---------------------------------------------------------------------------
// ws layout (bytes)
#define OFF_H     ((size_t)0)             // [2][B][H] bf16 h double-buffer (1 MB)
#define OFF_CNT   ((size_t)1048576)       // [8][32] int per-WG monotonic flags
#define OFF_WHHHI ((size_t)1081344)       // [H][H] bf16 (2 MB)
#define OFF_WHHLO ((size_t)3178496)       // [H][H] bf16 (2 MB)
#define OFF_WIH   ((size_t)5275648)       // [H][E] f16 (2 MB)
#define OFF_WCLF  ((size_t)7372800)       // [O][H] bf16 (1 MB)
#define OFF_EMB   ((size_t)8421376)       // [V][E] f16 (62.5 MB)
#define WS_MIN    ((size_t)8421376)
#define WS_FULL   ((size_t)73957376)

// ---------------------------------------------------------------------------
__global__ void init_zero_kernel(i32x4* __restrict__ p, int n4) {
  int i = blockIdx.x * 256 + threadIdx.x;
  if (i < n4) p[i] = (i32x4){0, 0, 0, 0};
}

// f32 -> (bf16 hi, bf16 lo) split: hi+lo carries ~17 mantissa bits.
__global__ void k_split_bf16(const float* __restrict__ s, bf16* __restrict__ hi,
                             bf16* __restrict__ lo, int n) {
  int i = blockIdx.x * 256 + threadIdx.x;
  if (i < n) {
    float v = s[i];
    bf16 h = __float2bfloat16(v);
    hi[i] = h;
    lo[i] = __float2bfloat16(v - __bfloat162float(h));
  }
}

__global__ void k_cvt_f16(const float* __restrict__ s, f16* __restrict__ d, int n) {
  int i = blockIdx.x * 256 + threadIdx.x;
  if (i < n) d[i] = (f16)s[i];
}

__global__ void k_cvt_bf16(const float* __restrict__ s, bf16* __restrict__ d, int n) {
  int i = blockIdx.x * 256 + threadIdx.x;
  if (i < n) d[i] = __float2bfloat16(s[i]);
}

// ---------------------------------------------------------------------------
// Persistent fused RNN scan, round 6 = round 5 with the asm constraint bug
// fixed. r5 crashed because the 16-load block lacked early-clobbers: the
// allocator could alias an output quad with the address pair %16; load 0's
// completion then clobbered the address mid-block -> wild loads -> fault.
// All asm load outputs are now "=&v" (early-clobber, disjoint from inputs).
//
// Design (from r4 post-mortem): r4's 20.6k cyc/step ~= 32 serialized MALL
// RTTs (compiler gave each per-lane atomic h-load its own vmcnt(0)). Fix:
// one asm block issues all 16 sc0+sc1 (MALL-coherent, L1/L2-bypass) 16B
// loads back-to-back with ONE s_waitcnt -> 1 RTT per step.
// Sync: per-WG monotonic flag, plain sc-bypass store after explicit drain;
// consumers poll 32 flags (one 4B load/lane) + __ballot. flag >= t ==> that
// producer finished reading h_{t-1} and writing h_t (double-buffer safe).
// 256 WGs = 8 chains (gi, 32 batch rows) x 32 col-groups; 4 waves = 2
// row-halves x 2 K-halves; Whh-hi slice LDS-resident (XOR-swizzled),
// Whh-lo + Wih fragments loop-invariant in unified VGPR/AGPR file.
__global__ __launch_bounds__(256, 1) void rnn_scan(
    const int* __restrict__ x,           // [B][S]
    const float* __restrict__ emb_f32,   // [V][E] f32
    const f16* __restrict__ emb_h,       // [V][E] f16 (optional)
    const int use_f16_emb,
    const f16* __restrict__ wih_h,       // [H][E] f16
    const float* __restrict__ bih, const float* __restrict__ bhh,
    const bf16* __restrict__ whh_hi_g,   // [H][H]
    const bf16* __restrict__ whh_lo_g,   // [H][H]
    bf16* __restrict__ hbuf,             // [2][B][H]
    int* __restrict__ flg) {             // [8][32]
  __shared__ short Wl[32 * 1024];  // Whh-hi slice, 16B-chunk XOR swizzle (64 KB)
  __shared__ f32x4 redA[128];      // kh1 -> kh0 partials (tile0)
  __shared__ f32x4 redB[128];      // kh0 -> kh1 partials (tile1)

  const int tid = threadIdx.x, lane = tid & 63;
  const int w = tid >> 6, wm = w & 1, kh = w >> 1;
  const int gi = blockIdx.x & 7, gj = blockIdx.x >> 3;
  const int m0 = gi * 32, n0 = gj * 32;
  const int am = lane & 15, akc = lane >> 4;

  // Stage Whh-hi rows (= h-cols) n0..n0+31, chunk c -> c ^ (row & 7)
  for (int q = tid; q < 32 * 128; q += 256) {
    int rr = q >> 7, c = q & 127;
    *(bf16x8*)&Wl[rr * 1024 + (c ^ (rr & 7)) * 8] =
        *(const bf16x8*)&whh_hi_g[(size_t)(n0 + rr) * H_ + c * 8];
  }

  // Per-wave K-half fragments: Whh-lo (bf16) + Wih (f16), both 16-col tiles.
  bf16x8 wlo[2][16];
  f16x8 wih[2][16];
  float bsum[2];
#pragma unroll
  for (int ct = 0; ct < 2; ++ct) {
    const int n = n0 + ct * 16 + am;
    bsum[ct] = bih[n] + bhh[n];
#pragma unroll
    for (int kc = 0; kc < 16; ++kc) {
      const int k = kh * 512 + kc * 32 + akc * 8;
      wlo[ct][kc] = *(const bf16x8*)&whh_lo_g[(size_t)n * H_ + k];
      wih[ct][kc] = *(const f16x8*)&wih_h[(size_t)n * E_ + k];
    }
  }
  __syncthreads();

  const int nl0 = am, nl1 = 16 + am;          // local Whh-hi rows (B-frags)
  const int sw0 = nl0 & 7, sw1 = nl1 & 7;
  const int arow = m0 + wm * 16 + am;         // this lane's A-frag batch row
  const int koff = kh * 512 + akc * 8;
  // D layout (m89/m91): col = lane&15, row = (lane>>4)*4 + reg
  const int mG = m0 + wm * 16 + (lane >> 4) * 4;
  const int nGm = n0 + kh * 16 + am;          // my store column (kh owns a tile)
  const int* fp = flg + (gi << 5) + (lane & 31);
  int* fpw = flg + (gi << 5) + gj;

  for (int t = 0; t < S_; ++t) {
    f32x4 a0a = {0.f,0.f,0.f,0.f}, a0b = {0.f,0.f,0.f,0.f};
    f32x4 a1a = {0.f,0.f,0.f,0.f}, a1b = {0.f,0.f,0.f,0.f};

    // ---- input projection (f16, cached loads): overlaps the wait below
    const int idx = x[arow * S_ + t];
    if (use_f16_emb) {
      const f16* er = emb_h + (size_t)idx * E_ + koff;
#pragma unroll
      for (int kc = 0; kc < 16; ++kc) {
        f16x8 a = *(const f16x8*)(er + kc * 32);
        a0a = mfma_h(a, wih[0][kc], a0a);
        a1a = mfma_h(a, wih[1][kc], a1a);
      }
    } else {
      const float* er = emb_f32 + (size_t)idx * E_ + koff;
#pragma unroll
      for (int kc = 0; kc < 16; ++kc) {
        f32x8 v = *(const f32x8*)(er + kc * 32);
        f16x8 a = __builtin_convertvector(v, f16x8);
        a0a = mfma_h(a, wih[0][kc], a0a);
        a1a = mfma_h(a, wih[1][kc], a1a);
      }
    }

    // ---- wait: all 32 producers of chain gi have published h_t
    if (t > 0) {
      int fv;
      for (;;) {
        asm volatile(
            "global_load_dword %0, %1, off sc0 sc1\n\t"
            "s_waitcnt vmcnt(0)"
            : "=&v"(fv) : "v"(fp) : "memory");
        if (__ballot(fv >= t) == ~0ull) break;
        __builtin_amdgcn_s_sleep(1);
      }
    }

    // ---- bulk h-fragment load: 16 pipelined sc-bypass 16B loads, ONE drain.
    // "=&v" early-clobber: outputs must not alias the address pair (loads
    // complete asynchronously; an aliased output would clobber %16 mid-block).
    const bf16* hsrc = hbuf + (size_t)(t & 1) * (B_ * H_) +
                       (size_t)arow * H_ + koff;
    i32x4 q0,q1,q2,q3,q4,q5,q6,q7,q8,q9,q10,q11,q12,q13,q14,q15;
    asm volatile(
        "global_load_dwordx4 %0, %16, off sc0 sc1\n\t"
        "global_load_dwordx4 %1, %16, off offset:64 sc0 sc1\n\t"
        "global_load_dwordx4 %2, %16, off offset:128 sc0 sc1\n\t"
        "global_load_dwordx4 %3, %16, off offset:192 sc0 sc1\n\t"
        "global_load_dwordx4 %4, %16, off offset:256 sc0 sc1\n\t"
        "global_load_dwordx4 %5, %16, off offset:320 sc0 sc1\n\t"
        "global_load_dwordx4 %6, %16, off offset:384 sc0 sc1\n\t"
        "global_load_dwordx4 %7, %16, off offset:448 sc0 sc1\n\t"
        "global_load_dwordx4 %8, %16, off offset:512 sc0 sc1\n\t"
        "global_load_dwordx4 %9, %16, off offset:576 sc0 sc1\n\t"
        "global_load_dwordx4 %10, %16, off offset:640 sc0 sc1\n\t"
        "global_load_dwordx4 %11, %16, off offset:704 sc0 sc1\n\t"
        "global_load_dwordx4 %12, %16, off offset:768 sc0 sc1\n\t"
        "global_load_dwordx4 %13, %16, off offset:832 sc0 sc1\n\t"
        "global_load_dwordx4 %14, %16, off offset:896 sc0 sc1\n\t"
        "global_load_dwordx4 %15, %16, off offset:960 sc0 sc1\n\t"
        "s_waitcnt vmcnt(0)"
        : "=&v"(q0), "=&v"(q1), "=&v"(q2), "=&v"(q3), "=&v"(q4), "=&v"(q5),
          "=&v"(q6), "=&v"(q7), "=&v"(q8), "=&v"(q9), "=&v"(q10), "=&v"(q11),
          "=&v"(q12), "=&v"(q13), "=&v"(q14), "=&v"(q15)
        : "v"(hsrc)
        : "memory");

    // ---- recurrent: h @ Whh^T, 2-pass (hi from LDS, lo from registers)
#define RSTEP(KC, QQ)                                                     \
    {                                                                     \
      icast _c; _c.i = (QQ);                                              \
      bf16x8 a = _c.h;                                                    \
      const int cidx = kh * 64 + (KC) * 4 + akc;                          \
      bf16x8 b0 = *(const bf16x8*)&Wl[nl0 * 1024 + (cidx ^ sw0) * 8];     \
      bf16x8 b1 = *(const bf16x8*)&Wl[nl1 * 1024 + (cidx ^ sw1) * 8];     \
      a0a = mfma_bf(a, b0, a0a);                                          \
      a0b = mfma_bf(a, wlo[0][KC], a0b);                                  \
      a1a = mfma_bf(a, b1, a1a);                                          \
      a1b = mfma_bf(a, wlo[1][KC], a1b);                                  \
    }
    RSTEP(0, q0)   RSTEP(1, q1)   RSTEP(2, q2)   RSTEP(3, q3)
    RSTEP(4, q4)   RSTEP(5, q5)   RSTEP(6, q6)   RSTEP(7, q7)
    RSTEP(8, q8)   RSTEP(9, q9)   RSTEP(10, q10) RSTEP(11, q11)
    RSTEP(12, q12) RSTEP(13, q13) RSTEP(14, q14) RSTEP(15, q15)
#undef RSTEP

    // ---- K-half exchange through LDS; each half finalizes one 16-col tile
    f32x4 acc0 = a0a + a0b, acc1 = a1a + a1b;
    if (kh == 1) redA[tid & 127] = acc0; else redB[tid] = acc1;
    __syncthreads();
    f32x4 fin = (kh == 0) ? (acc0 + redA[tid]) : (acc1 + redB[tid & 127]);

    // ---- tanh + sc-bypass h store (4 shorts), explicit drain
    bf16* hdst = hbuf + (size_t)((t + 1) & 1) * (B_ * H_);
    const float bs = bsum[kh];
    unsigned d0 = __bfloat16_as_ushort(__float2bfloat16(tanhf(fin[0] + bs)));
    unsigned d1 = __bfloat16_as_ushort(__float2bfloat16(tanhf(fin[1] + bs)));
    unsigned d2 = __bfloat16_as_ushort(__float2bfloat16(tanhf(fin[2] + bs)));
    unsigned d3 = __bfloat16_as_ushort(__float2bfloat16(tanhf(fin[3] + bs)));
    const bf16* sa0 = hdst + (size_t)mG * H_ + nGm;       // rows mG, mG+1
    const bf16* sa1 = sa0 + 2 * H_;                       // rows mG+2, mG+3
    asm volatile(
        "global_store_short %0, %2, off sc0 sc1\n\t"
        "global_store_short %0, %3, off offset:2048 sc0 sc1\n\t"
        "global_store_short %1, %4, off sc0 sc1\n\t"
        "global_store_short %1, %5, off offset:2048 sc0 sc1\n\t"
        "s_waitcnt vmcnt(0)"
        :: "v"(sa0), "v"(sa1), "v"(d0), "v"(d1), "v"(d2), "v"(d3)
        : "memory");

    __syncthreads();  // every lane's stores already drained -> WG h_t+1 done
    if (tid == 0) {
      int fo = t + 1;
      asm volatile("global_store_dword %0, %1, off sc0 sc1"
                   :: "v"(fpw), "v"(fo) : "memory");
    }
  }
}

// ---------------------------------------------------------------------------
// 128x128-tile bf16 GEMM (m97 structure): out[r][n] = sum_k A[r][k]*Bw[n][k]
// + bias[n]. f32 bias, f32 out.
__global__ __launch_bounds__(256, 2) void gemm_bias_kernel(
    const bf16* __restrict__ A, const bf16* __restrict__ Bw,
    const float* __restrict__ bias, float* __restrict__ Cc, int Ndim, int Kdim) {
  __shared__ bf16 At[128 * 64];
  __shared__ bf16 Bt[128 * 64];

  const int tid = threadIdx.x;
  const int wave = tid >> 6, lane = tid & 63;
  const int row0 = blockIdx.y * 128, col0 = blockIdx.x * 128;
  const int wm = wave & 1, wn = wave >> 1;

  f32x4 acc[4][4];
#pragma unroll
  for (int mi = 0; mi < 4; ++mi)
#pragma unroll
    for (int ni = 0; ni < 4; ++ni) acc[mi][ni] = (f32x4){0.f, 0.f, 0.f, 0.f};

  for (int kb = 0; kb < Kdim; kb += 64) {
#pragma unroll
    for (int it = 0; it < 4; ++it) {
      int q = it * 256 + tid;
      int rr = q >> 3, qc = (q & 7) * 8;
      const bf16* ga = A + (size_t)(row0 + rr) * Kdim + kb + qc;
      const bf16* gb = Bw + (size_t)(col0 + rr) * Kdim + kb + qc;
#if HAS_GLL
      __builtin_amdgcn_global_load_lds(
          (const __attribute__((address_space(1))) void*)ga,
          (__attribute__((address_space(3))) void*)((char*)At + (it * 4 + wave) * 1024),
          16, 0, 0);
      __builtin_amdgcn_global_load_lds(
          (const __attribute__((address_space(1))) void*)gb,
          (__attribute__((address_space(3))) void*)((char*)Bt + (it * 4 + wave) * 1024),
          16, 0, 0);
#else
      *(i32x4*)((char*)At + q * 16) = *(const i32x4*)ga;
      *(i32x4*)((char*)Bt + q * 16) = *(const i32x4*)gb;
#endif
    }
    __syncthreads();

#pragma unroll
    for (int ks = 0; ks < 2; ++ks) {
      const int ko = ks * 32 + (lane >> 4) * 8;
      bf16x8 af[4], bfr[4];
#pragma unroll
      for (int mi = 0; mi < 4; ++mi)
        af[mi] = *(const bf16x8*)&At[(wm * 64 + mi * 16 + (lane & 15)) * 64 + ko];
#pragma unroll
      for (int ni = 0; ni < 4; ++ni)
        bfr[ni] = *(const bf16x8*)&Bt[(wn * 64 + ni * 16 + (lane & 15)) * 64 + ko];
#pragma unroll
      for (int mi = 0; mi < 4; ++mi)
#pragma unroll
        for (int ni = 0; ni < 4; ++ni)
          acc[mi][ni] = mfma_bf(af[mi], bfr[ni], acc[mi][ni]);
    }
    __syncthreads();
  }

  const int crow = (lane >> 4) * 4, ccol = lane & 15;
#pragma unroll
  for (int ni = 0; ni < 4; ++ni) {
    const int gc = col0 + wn * 64 + ni * 16 + ccol;
    const float bv = bias[gc];
#pragma unroll
    for (int mi = 0; mi < 4; ++mi) {
      const int gr0 = row0 + wm * 64 + mi * 16 + crow;
#pragma unroll
      for (int r = 0; r < 4; ++r)
        Cc[(size_t)(gr0 + r) * Ndim + gc] = acc[mi][ni][r] + bv;
    }
  }
}

// ---------------------------------------------------------------------------
extern "C" void kernel_launch(void* const* d_in, const int* in_sizes, int n_in,
                              void* d_out, int out_size, void* d_ws, size_t ws_size,
                              hipStream_t stream) {
  const int*   x    = (const int*)d_in[0];
  const float* emb  = (const float*)d_in[1];
  const float* Wih  = (const float*)d_in[2];
  const float* bih  = (const float*)d_in[3];
  const float* Whh  = (const float*)d_in[4];
  const float* bhh  = (const float*)d_in[5];
  const float* Wclf = (const float*)d_in[6];
  const float* bclf = (const float*)d_in[7];
  float* out = (float*)d_out;

  char* ws = (char*)d_ws;
  bf16* hbuf   = (bf16*)(ws + OFF_H);
  int*  flg    = (int*)(ws + OFF_CNT);
  bf16* whh_hi = (bf16*)(ws + OFF_WHHHI);
  bf16* whh_lo = (bf16*)(ws + OFF_WHHLO);
  f16*  wih_h  = (f16*)(ws + OFF_WIH);
  bf16* wclf_b = (bf16*)(ws + OFF_WCLF);
  f16*  emb_h  = (f16*)(ws + OFF_EMB);
  const int use_f16_emb = (ws_size >= WS_FULL) ? 1 : 0;  // constant per session

  // zero hbuf + flags: (1048576 + 16416)/16 = 66562 int4s
  init_zero_kernel<<<dim3(261), dim3(256), 0, stream>>>((i32x4*)ws, 66562);

  // weight conversions (f32 inputs -> MFMA-ready formats in ws)
  k_split_bf16<<<dim3(4096), dim3(256), 0, stream>>>(Whh, whh_hi, whh_lo, H_ * H_);
  k_cvt_f16<<<dim3(4096), dim3(256), 0, stream>>>(Wih, wih_h, H_ * E_);
  k_cvt_bf16<<<dim3(2048), dim3(256), 0, stream>>>(Wclf, wclf_b, O_ * H_);
  if (use_f16_emb)
    k_cvt_f16<<<dim3((V_ * E_ + 255) / 256), dim3(256), 0, stream>>>(emb, emb_h,
                                                                     V_ * E_);

  // 512-step fused scan; final h lands in buffer (512)&1 == 0
  rnn_scan<<<dim3(256), dim3(256), 0, stream>>>(
      x, emb, emb_h, use_f16_emb, wih_h, bih, bhh, whh_hi, whh_lo, hbuf, flg);

  // out[b][o] = sum_k h[b][k] * Wclf[o][k] + bclf[o]
  gemm_bias_kernel<<<dim3(O_ / 128, B_ / 128), dim3(256), 0, stream>>>(
      hbuf, wclf_b, bclf, out, O_, H_);
}